// Round 4
// baseline (1600.234 us; speedup 1.0000x reference)
//
#include <hip/hip_runtime.h>
#include <hip/hip_bf16.h>
#include <math.h>

typedef unsigned short u16;
typedef unsigned int   u32;

#define L_LEAF 131072
#define N_ALL  262143

__device__ __forceinline__ float b2f(u16 u) {
    u32 x = ((u32)u) << 16;
    return __builtin_bit_cast(float, x);
}
__device__ __forceinline__ float lo2f(u32 p) { u32 x = p << 16;          return __builtin_bit_cast(float, x); }
__device__ __forceinline__ float hi2f(u32 p) { u32 x = p & 0xffff0000u;  return __builtin_bit_cast(float, x); }
__device__ __forceinline__ u16 f2b(float f) {
    u32 x = __builtin_bit_cast(u32, f);
    u32 r = x + 0x7fffu + ((x >> 16) & 1u);
    return (u16)(r >> 16);
}
__device__ __forceinline__ u32 pack2(float a, float b) {
    return (u32)f2b(a) | ((u32)f2b(b) << 16);
}
__device__ __forceinline__ float sigm(float x) { return 1.f / (1.f + expf(-x)); }

// ---------------------------------------------------------------------------
// K0: repack weights (f32 in) -> bf16, k-major, k-paired.
//  WtL2: [150][384][2]  (leaf: i|o|u stacked along 384; pair = (k=2kk, 2kk+1))
//  WtT2: [128][384][2]  (tree i|o|u, k<256 = [lh;rh] part of Ui/Uo/Uu)
//  WtF2: [128][128][2]  (k<128 -> Uf1, k>=128 -> Uf2)
// ---------------------------------------------------------------------------
__global__ __launch_bounds__(256) void k_prep(
    const float* __restrict__ Wi_w, const float* __restrict__ Wo_w, const float* __restrict__ Wu_w,
    const float* __restrict__ Ui_w, const float* __restrict__ Uo_w, const float* __restrict__ Uu_w,
    const float* __restrict__ Uf1_w, const float* __restrict__ Uf2_w,
    u16* __restrict__ WtL2, u16* __restrict__ WtT2, u16* __restrict__ WtF2)
{
    int gid = blockIdx.x * 256 + threadIdx.x;
    if (gid < 115200) {                       // 150*384*2
        int c = gid & 1, t = gid >> 1;
        int dd = t % 384, kk = t / 384;
        int k = 2 * kk + c;
        float v = (dd < 128) ? Wi_w[dd * 300 + k]
                : (dd < 256) ? Wo_w[(dd - 128) * 300 + k]
                             : Wu_w[(dd - 256) * 300 + k];
        WtL2[gid] = f2b(v);
    } else if (gid < 213504) {                // + 128*384*2
        int g = gid - 115200;
        int c = g & 1, t = g >> 1;
        int dd = t % 384, kk = t / 384;
        int k = 2 * kk + c;
        float v = (dd < 128) ? Ui_w[dd * 384 + k]
                : (dd < 256) ? Uo_w[(dd - 128) * 384 + k]
                             : Uu_w[(dd - 256) * 384 + k];
        WtT2[g] = f2b(v);
    } else if (gid < 246272) {                // + 128*128*2
        int g = gid - 213504;
        int c = g & 1, t = g >> 1;
        int d = t % 128, kk = t / 128;
        int k = 2 * kk + c;
        float v = (k < 128) ? Uf1_w[d * 128 + k] : Uf2_w[d * 128 + (k - 128)];
        WtF2[g] = f2b(v);
    }
}

// ---------------------------------------------------------------------------
// K1: xz[t][j] = lstm_wih[j,:] @ emb[targets[t]] + bih[j] + bhh[j]   (f32)
// ---------------------------------------------------------------------------
__global__ __launch_bounds__(256) void k_xz(
    const float* __restrict__ emb, const float* __restrict__ wih,
    const float* __restrict__ bih, const float* __restrict__ bhh,
    const int* __restrict__ targets, float* __restrict__ xz)
{
    __shared__ float te[300];
    int t = blockIdx.x, tid = threadIdx.x;
    int tgt = targets[t];
    if (tid < 75) {
        float4 v = *(const float4*)(emb + (size_t)tgt * 300 + tid * 4);
        te[tid * 4 + 0] = v.x; te[tid * 4 + 1] = v.y;
        te[tid * 4 + 2] = v.z; te[tid * 4 + 3] = v.w;
    }
    __syncthreads();
    for (int rep = 0; rep < 2; ++rep) {
        int j = tid + rep * 256;
        float acc = bih[j] + bhh[j];
        const float* wr = wih + (size_t)j * 300;
        for (int k4 = 0; k4 < 75; ++k4) {
            float4 wv = *(const float4*)(wr + k4 * 4);
            float4 tv = *(const float4*)&te[k4 * 4];
            acc = fmaf(wv.x, tv.x, acc);
            acc = fmaf(wv.y, tv.y, acc);
            acc = fmaf(wv.z, tv.z, acc);
            acc = fmaf(wv.w, tv.w, acc);
        }
        xz[t * 512 + j] = acc;
    }
}

// ---------------------------------------------------------------------------
// K2: sequential LSTM (50 steps) + tb[g*128+d] = U?_w[d,256:384]@th + U?_b[d]
// One block, 256 threads; whh (f32) packed to bf16 pairs in registers.
// ---------------------------------------------------------------------------
__global__ __launch_bounds__(256) void k_lstm(
    const float* __restrict__ whh, const float* __restrict__ xz,
    const float* __restrict__ Ui_w, const float* __restrict__ Uo_w, const float* __restrict__ Uu_w,
    const float* __restrict__ Ui_b, const float* __restrict__ Uo_b, const float* __restrict__ Uu_b,
    float* __restrict__ tb)
{
    __shared__ float h_lds[128];
    __shared__ float z_lds[512];
    int tid = threadIdx.x;

    u32 w0[64], w1[64];
    #pragma unroll
    for (int k2 = 0; k2 < 64; ++k2) {
        w0[k2] = pack2(whh[(size_t)tid * 128 + 2 * k2],
                       whh[(size_t)tid * 128 + 2 * k2 + 1]);
        w1[k2] = pack2(whh[(size_t)(tid + 256) * 128 + 2 * k2],
                       whh[(size_t)(tid + 256) * 128 + 2 * k2 + 1]);
    }
    float c0 = 0.f;
    if (tid < 128) h_lds[tid] = 0.f;
    __syncthreads();

    for (int t = 0; t < 50; ++t) {
        float a0 = xz[t * 512 + tid];
        float a1 = xz[t * 512 + tid + 256];
        #pragma unroll
        for (int k2 = 0; k2 < 64; k2 += 2) {
            float4 hv = *(const float4*)&h_lds[k2 * 2];
            a0 = fmaf(lo2f(w0[k2]),     hv.x, a0);
            a0 = fmaf(hi2f(w0[k2]),     hv.y, a0);
            a0 = fmaf(lo2f(w0[k2 + 1]), hv.z, a0);
            a0 = fmaf(hi2f(w0[k2 + 1]), hv.w, a0);
            a1 = fmaf(lo2f(w1[k2]),     hv.x, a1);
            a1 = fmaf(hi2f(w1[k2]),     hv.y, a1);
            a1 = fmaf(lo2f(w1[k2 + 1]), hv.z, a1);
            a1 = fmaf(hi2f(w1[k2 + 1]), hv.w, a1);
        }
        z_lds[tid] = a0;
        z_lds[tid + 256] = a1;
        __syncthreads();
        if (tid < 128) {
            float zi = z_lds[tid], zf = z_lds[128 + tid];
            float zg = z_lds[256 + tid], zo = z_lds[384 + tid];
            c0 = sigm(zf) * c0 + sigm(zi) * tanhf(zg);
            h_lds[tid] = sigm(zo) * tanhf(c0);
        }
        __syncthreads();
    }

    for (int rep = 0; rep < 2; ++rep) {
        int j = tid + rep * 256;
        if (j >= 384) break;
        int g = j >> 7, dd = j & 127;
        const float* W = (g == 0) ? Ui_w : (g == 1) ? Uo_w : Uu_w;
        const float* B = (g == 0) ? Ui_b : (g == 1) ? Uo_b : Uu_b;
        float acc = B[dd];
        for (int k = 0; k < 128; ++k)
            acc = fmaf(W[dd * 384 + 256 + k], h_lds[k], acc);
        tb[j] = acc;
    }
}

// ---------------------------------------------------------------------------
// K3: leaf layer. 16 rows/block; thread = (wave q -> rows q*4..q*4+3,
// lane d2 -> dims d2 and d2+64). emb rows (f32) transposed into LDS.
// ---------------------------------------------------------------------------
__global__ __launch_bounds__(256) void k_leaf(
    const float* __restrict__ emb, const int* __restrict__ toks,
    const u16* __restrict__ WtL2,
    const float* __restrict__ Wi_b, const float* __restrict__ Wo_b, const float* __restrict__ Wu_b,
    u16* __restrict__ h_all, u16* __restrict__ c_all)
{
    __shared__ float eT[300][16];
    const int tid = threadIdx.x;
    const int b = blockIdx.x;
    const int q = tid >> 6, d2 = tid & 63;
    const int r0 = q * 4;

    for (int idx = tid; idx < 16 * 75; idx += 256) {
        int row = idx & 15, kk = idx >> 4;
        int tok = toks[b * 16 + row];
        float4 v = *(const float4*)(emb + (size_t)tok * 300 + kk * 4);
        eT[kk * 4 + 0][row] = v.x;
        eT[kk * 4 + 1][row] = v.y;
        eT[kk * 4 + 2][row] = v.z;
        eT[kk * 4 + 3][row] = v.w;
    }
    __syncthreads();

    float acc[3][4][2];
    #pragma unroll
    for (int m = 0; m < 3; ++m)
        #pragma unroll
        for (int j = 0; j < 4; ++j) { acc[m][j][0] = 0.f; acc[m][j][1] = 0.f; }

    const u32* WL = (const u32*)WtL2;
    for (int kk = 0; kk < 150; ++kk) {
        u32 wp[3][2];
        wp[0][0] = WL[kk * 384 + d2];        wp[0][1] = WL[kk * 384 + d2 + 64];
        wp[1][0] = WL[kk * 384 + 128 + d2];  wp[1][1] = WL[kk * 384 + 128 + d2 + 64];
        wp[2][0] = WL[kk * 384 + 256 + d2];  wp[2][1] = WL[kk * 384 + 256 + d2 + 64];
        float4 t0 = *(const float4*)&eT[2 * kk][r0];
        float4 t1 = *(const float4*)&eT[2 * kk + 1][r0];
        float xs0[4] = {t0.x, t0.y, t0.z, t0.w};
        float xs1[4] = {t1.x, t1.y, t1.z, t1.w};
        #pragma unroll
        for (int m = 0; m < 3; ++m)
            #pragma unroll
            for (int h2 = 0; h2 < 2; ++h2) {
                float wl = lo2f(wp[m][h2]), wh = hi2f(wp[m][h2]);
                #pragma unroll
                for (int j = 0; j < 4; ++j)
                    acc[m][j][h2] = fmaf(wl, xs0[j], fmaf(wh, xs1[j], acc[m][j][h2]));
            }
    }

    float bi[2] = {Wi_b[d2], Wi_b[d2 + 64]};
    float bo[2] = {Wo_b[d2], Wo_b[d2 + 64]};
    float bu[2] = {Wu_b[d2], Wu_b[d2 + 64]};
    #pragma unroll
    for (int j = 0; j < 4; ++j) {
        int row = b * 16 + r0 + j;
        #pragma unroll
        for (int h2 = 0; h2 < 2; ++h2) {
            int d = d2 + h2 * 64;
            float iv = sigm(acc[0][j][h2] + bi[h2]);
            float ov = sigm(acc[1][j][h2] + bo[h2]);
            float uv = fmaxf(acc[2][j][h2] + bu[h2], 0.f);
            float cv = iv * uv;
            float hv = ov * fmaxf(cv, 0.f);
            h_all[(size_t)row * 128 + d] = f2b(hv);
            c_all[(size_t)row * 128 + d] = f2b(cv);
        }
    }
}

// ---------------------------------------------------------------------------
// K4: one tree level. n_out output rows; inputs rows [2r],[2r+1] of prev level.
// ---------------------------------------------------------------------------
__global__ __launch_bounds__(256) void k_tree(
    const u16* __restrict__ WtT2, const u16* __restrict__ WtF2,
    const float* __restrict__ tb,
    const float* __restrict__ Uf1_b, const float* __restrict__ Uf2_b,
    u16* __restrict__ h_all, u16* __restrict__ c_all,
    int in_off, int out_off, int n_out)
{
    __shared__ float xT[256][16];
    const int tid = threadIdx.x;
    const int b = blockIdx.x;
    const int q = tid >> 6, d2 = tid & 63;
    const int r0 = q * 4;
    const int base = b * 16;

    for (int idx = tid; idx < 1024; idx += 256) {
        int row2 = idx & 31, qq = idx >> 5;
        if (base * 2 + row2 < 2 * n_out) {
            ushort4 v = *(const ushort4*)(h_all + ((size_t)(in_off + base * 2 + row2)) * 128 + qq * 4);
            int kb = (row2 & 1) * 128 + qq * 4;
            int rr = row2 >> 1;
            xT[kb + 0][rr] = b2f(v.x); xT[kb + 1][rr] = b2f(v.y);
            xT[kb + 2][rr] = b2f(v.z); xT[kb + 3][rr] = b2f(v.w);
        }
    }
    __syncthreads();

    float acc[3][4][2];
    float accf0[4][2], accf1[4][2];
    #pragma unroll
    for (int j = 0; j < 4; ++j) {
        #pragma unroll
        for (int h2 = 0; h2 < 2; ++h2) {
            acc[0][j][h2] = 0.f; acc[1][j][h2] = 0.f; acc[2][j][h2] = 0.f;
            accf0[j][h2] = 0.f;  accf1[j][h2] = 0.f;
        }
    }

    const u32* WT = (const u32*)WtT2;
    const u32* WF = (const u32*)WtF2;

    auto do_half = [&](int kk0, float (&af)[4][2]) {
        for (int kk = kk0; kk < kk0 + 64; ++kk) {
            u32 wp[4][2];
            wp[0][0] = WT[kk * 384 + d2];        wp[0][1] = WT[kk * 384 + d2 + 64];
            wp[1][0] = WT[kk * 384 + 128 + d2];  wp[1][1] = WT[kk * 384 + 128 + d2 + 64];
            wp[2][0] = WT[kk * 384 + 256 + d2];  wp[2][1] = WT[kk * 384 + 256 + d2 + 64];
            wp[3][0] = WF[kk * 128 + d2];        wp[3][1] = WF[kk * 128 + d2 + 64];
            float4 t0 = *(const float4*)&xT[2 * kk][r0];
            float4 t1 = *(const float4*)&xT[2 * kk + 1][r0];
            float xs0[4] = {t0.x, t0.y, t0.z, t0.w};
            float xs1[4] = {t1.x, t1.y, t1.z, t1.w};
            #pragma unroll
            for (int m = 0; m < 3; ++m)
                #pragma unroll
                for (int h2 = 0; h2 < 2; ++h2) {
                    float wl = lo2f(wp[m][h2]), wh = hi2f(wp[m][h2]);
                    #pragma unroll
                    for (int j = 0; j < 4; ++j)
                        acc[m][j][h2] = fmaf(wl, xs0[j], fmaf(wh, xs1[j], acc[m][j][h2]));
                }
            #pragma unroll
            for (int h2 = 0; h2 < 2; ++h2) {
                float wl = lo2f(wp[3][h2]), wh = hi2f(wp[3][h2]);
                #pragma unroll
                for (int j = 0; j < 4; ++j)
                    af[j][h2] = fmaf(wl, xs0[j], fmaf(wh, xs1[j], af[j][h2]));
            }
        }
    };
    do_half(0, accf0);    // lh half -> f1
    do_half(64, accf1);   // rh half -> f2

    float tbi[2] = {tb[d2], tb[d2 + 64]};
    float tbo[2] = {tb[128 + d2], tb[128 + d2 + 64]};
    float tbu[2] = {tb[256 + d2], tb[256 + d2 + 64]};
    float fb1[2] = {Uf1_b[d2], Uf1_b[d2 + 64]};
    float fb2[2] = {Uf2_b[d2], Uf2_b[d2 + 64]};

    #pragma unroll
    for (int j = 0; j < 4; ++j) {
        int row = base + r0 + j;
        if (row < n_out) {
            #pragma unroll
            for (int h2 = 0; h2 < 2; ++h2) {
                int d = d2 + h2 * 64;
                float iv = sigm(acc[0][j][h2] + tbi[h2]);
                float ov = sigm(acc[1][j][h2] + tbo[h2]);
                float uv = fmaxf(acc[2][j][h2] + tbu[h2], 0.f);
                float f1 = sigm(accf0[j][h2] + fb1[h2]);
                float f2 = sigm(accf1[j][h2] + fb2[h2]);
                float lc = b2f(c_all[((size_t)(in_off + 2 * row)) * 128 + d]);
                float rc = b2f(c_all[((size_t)(in_off + 2 * row + 1)) * 128 + d]);
                float cv = iv * uv + f1 * lc + f2 * rc;
                float hv = ov * fmaxf(cv, 0.f);
                h_all[((size_t)(out_off + row)) * 128 + d] = f2b(hv);
                c_all[((size_t)(out_off + row)) * 128 + d] = f2b(cv);
            }
        }
    }
}

// ---------------------------------------------------------------------------
// K5: projection of all 262143 h rows -> (row, 3) f32 output.
// ---------------------------------------------------------------------------
__global__ __launch_bounds__(256) void k_proj(
    const u16* __restrict__ h_all, const float* __restrict__ proj_w,
    const float* __restrict__ proj_b, float* __restrict__ out)
{
    int tid = threadIdx.x;
    int lane = tid & 63;
    int gw = blockIdx.x * 4 + (tid >> 6);
    float pw[3][2], pb[3];
    #pragma unroll
    for (int j = 0; j < 3; ++j) {
        pw[j][0] = proj_w[j * 128 + 2 * lane];
        pw[j][1] = proj_w[j * 128 + 2 * lane + 1];
        pb[j] = proj_b[j];
    }
    for (int row = gw; row < N_ALL; row += 4096) {
        u32 hv = *(const u32*)&h_all[(size_t)row * 128 + 2 * lane];
        float h0 = lo2f(hv), h1 = hi2f(hv);
        float p0 = pw[0][0] * h0 + pw[0][1] * h1;
        float p1 = pw[1][0] * h0 + pw[1][1] * h1;
        float p2 = pw[2][0] * h0 + pw[2][1] * h1;
        #pragma unroll
        for (int off = 32; off > 0; off >>= 1) {
            p0 += __shfl_xor(p0, off);
            p1 += __shfl_xor(p1, off);
            p2 += __shfl_xor(p2, off);
        }
        if (lane == 0) {
            out[(size_t)row * 3 + 0] = p0 + pb[0];
            out[(size_t)row * 3 + 1] = p1 + pb[1];
            out[(size_t)row * 3 + 2] = p2 + pb[2];
        }
    }
}

// ---------------------------------------------------------------------------
extern "C" void kernel_launch(void* const* d_in, const int* in_sizes, int n_in,
                              void* d_out, int out_size, void* d_ws, size_t ws_size,
                              hipStream_t stream)
{
    const float* emb    = (const float*)d_in[0];
    const float* Wi_w   = (const float*)d_in[1];
    const float* Wi_b   = (const float*)d_in[2];
    const float* Wo_w   = (const float*)d_in[3];
    const float* Wo_b   = (const float*)d_in[4];
    const float* Wu_w   = (const float*)d_in[5];
    const float* Wu_b   = (const float*)d_in[6];
    const float* Ui_w   = (const float*)d_in[7];
    const float* Ui_b   = (const float*)d_in[8];
    const float* Uo_w   = (const float*)d_in[9];
    const float* Uo_b   = (const float*)d_in[10];
    const float* Uu_w   = (const float*)d_in[11];
    const float* Uu_b   = (const float*)d_in[12];
    const float* Uf1_w  = (const float*)d_in[13];
    const float* Uf1_b  = (const float*)d_in[14];
    const float* Uf2_w  = (const float*)d_in[15];
    const float* Uf2_b  = (const float*)d_in[16];
    const float* wih    = (const float*)d_in[17];
    const float* whh    = (const float*)d_in[18];
    const float* bih    = (const float*)d_in[19];
    const float* bhh    = (const float*)d_in[20];
    const float* proj_w = (const float*)d_in[21];
    const float* proj_b = (const float*)d_in[22];
    const int* toks     = (const int*)d_in[23];
    const int* tgts     = (const int*)d_in[24];

    char* ws = (char*)d_ws;
    u16*   h_all = (u16*)(ws);                    // 262144*128*2 = 67,108,864 B
    u16*   c_all = (u16*)(ws + 67108864);         // 67,108,864 B
    u16*   WtL2  = (u16*)(ws + 134217728);        // 230,400 B
    u16*   WtT2  = (u16*)(ws + 134448128);        // 196,608 B
    u16*   WtF2  = (u16*)(ws + 134644736);        // 65,536 B
    float* xz    = (float*)(ws + 134710272);      // 102,400 B
    float* tb    = (float*)(ws + 134812672);      // 1,536 B  -> total 134,814,208 B

    k_prep<<<962, 256, 0, stream>>>(Wi_w, Wo_w, Wu_w, Ui_w, Uo_w, Uu_w,
                                    Uf1_w, Uf2_w, WtL2, WtT2, WtF2);
    k_xz<<<50, 256, 0, stream>>>(emb, wih, bih, bhh, tgts, xz);
    k_lstm<<<1, 256, 0, stream>>>(whh, xz, Ui_w, Uo_w, Uu_w, Ui_b, Uo_b, Uu_b, tb);
    k_leaf<<<8192, 256, 0, stream>>>(emb, toks, WtL2, Wi_b, Wo_b, Wu_b, h_all, c_all);

    int in_off = 0, n = L_LEAF, out_off = L_LEAF;
    for (int lvl = 0; lvl < 17; ++lvl) {
        int n_out = n >> 1;
        int blocks = (n_out + 15) / 16;
        k_tree<<<blocks, 256, 0, stream>>>(WtT2, WtF2, tb, Uf1_b, Uf2_b,
                                           h_all, c_all, in_off, out_off, n_out);
        in_off = out_off; out_off += n_out; n = n_out;
    }

    k_proj<<<1024, 256, 0, stream>>>(h_all, proj_w, proj_b, (float*)d_out);
}

// Round 5
// 510.998 us; speedup vs baseline: 3.1316x; 3.1316x over previous
//
#include <hip/hip_runtime.h>
#include <hip/hip_bf16.h>
#include <math.h>

typedef unsigned short u16;
typedef unsigned int   u32;
typedef __attribute__((ext_vector_type(8))) short bf16x8;
typedef __attribute__((ext_vector_type(4))) float f32x4;

#define L_LEAF 131072
#define N_ALL  262143
#define KPL 328   // leaf A-tile LDS row stride (elems): 320 + 8 pad
#define KPT 264   // tree A/C-tile LDS row stride: 256 + 8 pad

__device__ __forceinline__ float b2f(u16 u) {
    u32 x = ((u32)u) << 16;
    return __builtin_bit_cast(float, x);
}
__device__ __forceinline__ float lo2f(u32 p) { u32 x = p << 16;          return __builtin_bit_cast(float, x); }
__device__ __forceinline__ float hi2f(u32 p) { u32 x = p & 0xffff0000u;  return __builtin_bit_cast(float, x); }
__device__ __forceinline__ u16 f2b(float f) {
    u32 x = __builtin_bit_cast(u32, f);
    u32 r = x + 0x7fffu + ((x >> 16) & 1u);
    return (u16)(r >> 16);
}
__device__ __forceinline__ u32 pack2(float a, float b) {
    return (u32)f2b(a) | ((u32)f2b(b) << 16);
}
__device__ __forceinline__ float sigm(float x) { return 1.f / (1.f + expf(-x)); }

// ---------------------------------------------------------------------------
// K0a: build leaf B-pack. BpkL[kc][nt][lane][8] bf16, kc<10, nt<24.
//  n = nt*16 + (lane&15): gate = n>>7 (0=i,1=o,2=u), d = n&127.
//  k = kc*32 + (lane>>4)*8 + j  (0 for k >= 300)
// ---------------------------------------------------------------------------
__global__ __launch_bounds__(256) void k_packL(
    const float* __restrict__ Wi_w, const float* __restrict__ Wo_w,
    const float* __restrict__ Wu_w, u16* __restrict__ BpkL)
{
    int gid = blockIdx.x * 256 + threadIdx.x;
    if (gid >= 15360) return;
    int l  = gid & 63;
    int nt = (gid >> 6) % 24;
    int kc = gid / (24 * 64);
    int n  = nt * 16 + (l & 15);
    int g  = n >> 7, d = n & 127;
    int k0 = kc * 32 + (l >> 4) * 8;
    const float* W = (g == 0) ? Wi_w : (g == 1) ? Wo_w : Wu_w;
    #pragma unroll
    for (int j = 0; j < 8; ++j) {
        int k = k0 + j;
        float v = (k < 300) ? W[d * 300 + k] : 0.f;
        BpkL[(size_t)gid * 8 + j] = f2b(v);
    }
}

// ---------------------------------------------------------------------------
// K0b: build tree B-pack. BpkT[kc][nt][lane][8] bf16, kc<8, nt<40.
//  gates: 0=i,1=o,2=u (k<256 = U?_w cols 0..255 = [lh;rh]), 3=f1 (k<128),
//  4=f2 (k>=128).
// ---------------------------------------------------------------------------
__global__ __launch_bounds__(256) void k_packT(
    const float* __restrict__ Ui_w, const float* __restrict__ Uo_w,
    const float* __restrict__ Uu_w, const float* __restrict__ Uf1_w,
    const float* __restrict__ Uf2_w, u16* __restrict__ BpkT)
{
    int gid = blockIdx.x * 256 + threadIdx.x;
    if (gid >= 20480) return;
    int l  = gid & 63;
    int nt = (gid >> 6) % 40;
    int kc = gid / (40 * 64);
    int n  = nt * 16 + (l & 15);
    int g  = n >> 7, d = n & 127;
    int k0 = kc * 32 + (l >> 4) * 8;
    #pragma unroll
    for (int j = 0; j < 8; ++j) {
        int k = k0 + j;
        float v;
        if (g == 0)      v = Ui_w[d * 384 + k];
        else if (g == 1) v = Uo_w[d * 384 + k];
        else if (g == 2) v = Uu_w[d * 384 + k];
        else if (g == 3) v = (k < 128)  ? Uf1_w[d * 128 + k]       : 0.f;
        else             v = (k >= 128) ? Uf2_w[d * 128 + (k-128)] : 0.f;
        BpkT[(size_t)gid * 8 + j] = f2b(v);
    }
}

// ---------------------------------------------------------------------------
// K1: xz[t][j] = lstm_wih[j,:] @ emb[targets[t]] + bih[j] + bhh[j]   (f32)
// ---------------------------------------------------------------------------
__global__ __launch_bounds__(256) void k_xz(
    const float* __restrict__ emb, const float* __restrict__ wih,
    const float* __restrict__ bih, const float* __restrict__ bhh,
    const int* __restrict__ targets, float* __restrict__ xz)
{
    __shared__ float te[300];
    int t = blockIdx.x, tid = threadIdx.x;
    int tgt = targets[t];
    if (tid < 75) {
        float4 v = *(const float4*)(emb + (size_t)tgt * 300 + tid * 4);
        te[tid * 4 + 0] = v.x; te[tid * 4 + 1] = v.y;
        te[tid * 4 + 2] = v.z; te[tid * 4 + 3] = v.w;
    }
    __syncthreads();
    for (int rep = 0; rep < 2; ++rep) {
        int j = tid + rep * 256;
        float acc = bih[j] + bhh[j];
        const float* wr = wih + (size_t)j * 300;
        for (int k4 = 0; k4 < 75; ++k4) {
            float4 wv = *(const float4*)(wr + k4 * 4);
            float4 tv = *(const float4*)&te[k4 * 4];
            acc = fmaf(wv.x, tv.x, acc);
            acc = fmaf(wv.y, tv.y, acc);
            acc = fmaf(wv.z, tv.z, acc);
            acc = fmaf(wv.w, tv.w, acc);
        }
        xz[t * 512 + j] = acc;
    }
}

// ---------------------------------------------------------------------------
// K2: sequential LSTM (50 steps) + tb[g*128+d] = U?_w[d,256:384]@th + U?_b[d]
// ---------------------------------------------------------------------------
__global__ __launch_bounds__(256) void k_lstm(
    const float* __restrict__ whh, const float* __restrict__ xz,
    const float* __restrict__ Ui_w, const float* __restrict__ Uo_w, const float* __restrict__ Uu_w,
    const float* __restrict__ Ui_b, const float* __restrict__ Uo_b, const float* __restrict__ Uu_b,
    float* __restrict__ tb)
{
    __shared__ float h_lds[128];
    __shared__ float z_lds[512];
    int tid = threadIdx.x;

    u32 w0[64], w1[64];
    #pragma unroll
    for (int k2 = 0; k2 < 64; ++k2) {
        w0[k2] = pack2(whh[(size_t)tid * 128 + 2 * k2],
                       whh[(size_t)tid * 128 + 2 * k2 + 1]);
        w1[k2] = pack2(whh[(size_t)(tid + 256) * 128 + 2 * k2],
                       whh[(size_t)(tid + 256) * 128 + 2 * k2 + 1]);
    }
    float c0 = 0.f;
    if (tid < 128) h_lds[tid] = 0.f;
    __syncthreads();

    for (int t = 0; t < 50; ++t) {
        float a0 = xz[t * 512 + tid];
        float a1 = xz[t * 512 + tid + 256];
        #pragma unroll
        for (int k2 = 0; k2 < 64; k2 += 2) {
            float4 hv = *(const float4*)&h_lds[k2 * 2];
            a0 = fmaf(lo2f(w0[k2]),     hv.x, a0);
            a0 = fmaf(hi2f(w0[k2]),     hv.y, a0);
            a0 = fmaf(lo2f(w0[k2 + 1]), hv.z, a0);
            a0 = fmaf(hi2f(w0[k2 + 1]), hv.w, a0);
            a1 = fmaf(lo2f(w1[k2]),     hv.x, a1);
            a1 = fmaf(hi2f(w1[k2]),     hv.y, a1);
            a1 = fmaf(lo2f(w1[k2 + 1]), hv.z, a1);
            a1 = fmaf(hi2f(w1[k2 + 1]), hv.w, a1);
        }
        z_lds[tid] = a0;
        z_lds[tid + 256] = a1;
        __syncthreads();
        if (tid < 128) {
            float zi = z_lds[tid], zf = z_lds[128 + tid];
            float zg = z_lds[256 + tid], zo = z_lds[384 + tid];
            c0 = sigm(zf) * c0 + sigm(zi) * tanhf(zg);
            h_lds[tid] = sigm(zo) * tanhf(c0);
        }
        __syncthreads();
    }

    for (int rep = 0; rep < 2; ++rep) {
        int j = tid + rep * 256;
        if (j >= 384) break;
        int g = j >> 7, dd = j & 127;
        const float* W = (g == 0) ? Ui_w : (g == 1) ? Uo_w : Uu_w;
        const float* B = (g == 0) ? Ui_b : (g == 1) ? Uo_b : Uu_b;
        float acc = B[dd];
        for (int k = 0; k < 128; ++k)
            acc = fmaf(W[dd * 384 + 256 + k], h_lds[k], acc);
        tb[j] = acc;
    }
}

// ---------------------------------------------------------------------------
// K3: leaf layer, MFMA. Block = 64 rows, 4 waves; wave w owns d in [32w,32w+32).
// A: gathered emb rows (f32->bf16) in LDS [64][KPL]. B: BpkL fragments (L2).
// ---------------------------------------------------------------------------
__global__ __launch_bounds__(256) void k_leaf(
    const float* __restrict__ emb, const int* __restrict__ toks,
    const bf16x8* __restrict__ BpkL,
    const float* __restrict__ Wi_b, const float* __restrict__ Wo_b, const float* __restrict__ Wu_b,
    u16* __restrict__ h_all, u16* __restrict__ c_all)
{
    __shared__ __align__(16) u16 Atile[64 * KPL];   // 41,984 B
    const int tid = threadIdx.x, b = blockIdx.x;

    {   // stage 64 rows; 4 threads per row
        int row = tid >> 2, sub = tid & 3;
        int tok = toks[b * 64 + row];
        const float* src = emb + (size_t)tok * 300;
        u16* dst = Atile + row * KPL;
        for (int i4 = sub; i4 < 75; i4 += 4) {
            float4 v = *(const float4*)(src + i4 * 4);
            ushort4 o;
            o.x = f2b(v.x); o.y = f2b(v.y); o.z = f2b(v.z); o.w = f2b(v.w);
            *(ushort4*)(dst + i4 * 4) = o;
        }
        if (sub == 0) {
            ushort4 z = {0, 0, 0, 0};
            #pragma unroll
            for (int p = 0; p < 5; ++p) *(ushort4*)(dst + 300 + p * 4) = z;
        }
    }
    __syncthreads();

    const int wv = tid >> 6, l = tid & 63;
    const int lm = l & 15, lk = l >> 4;

    f32x4 acc[3][2][4];
    #pragma unroll
    for (int g = 0; g < 3; ++g)
        #pragma unroll
        for (int ns = 0; ns < 2; ++ns)
            #pragma unroll
            for (int mt = 0; mt < 4; ++mt)
                acc[g][ns][mt] = (f32x4){0.f, 0.f, 0.f, 0.f};

    for (int kc = 0; kc < 10; ++kc) {
        bf16x8 a[4];
        #pragma unroll
        for (int mt = 0; mt < 4; ++mt)
            a[mt] = *(const bf16x8*)&Atile[(mt * 16 + lm) * KPL + kc * 32 + lk * 8];
        bf16x8 bf[3][2];
        #pragma unroll
        for (int g = 0; g < 3; ++g)
            #pragma unroll
            for (int ns = 0; ns < 2; ++ns) {
                int nt = g * 8 + wv * 2 + ns;
                bf[g][ns] = BpkL[(kc * 24 + nt) * 64 + l];
            }
        #pragma unroll
        for (int g = 0; g < 3; ++g)
            #pragma unroll
            for (int ns = 0; ns < 2; ++ns)
                #pragma unroll
                for (int mt = 0; mt < 4; ++mt)
                    acc[g][ns][mt] = __builtin_amdgcn_mfma_f32_16x16x32_bf16(
                        a[mt], bf[g][ns], acc[g][ns][mt], 0, 0, 0);
    }
    __syncthreads();

    // epilogue: gates -> c,h; stage bf16 tiles in LDS (reuse Atile), copy out.
    u16* Hs = Atile;               // [64][136]
    u16* Cs = Atile + 64 * 136;    // [64][136]; total 34,816 B <= 41,984 B
    float bi[2], bo[2], bu[2];
    #pragma unroll
    for (int ns = 0; ns < 2; ++ns) {
        int d = wv * 32 + ns * 16 + lm;
        bi[ns] = Wi_b[d]; bo[ns] = Wo_b[d]; bu[ns] = Wu_b[d];
    }
    #pragma unroll
    for (int mt = 0; mt < 4; ++mt)
        #pragma unroll
        for (int ns = 0; ns < 2; ++ns) {
            int d = wv * 32 + ns * 16 + lm;
            #pragma unroll
            for (int r = 0; r < 4; ++r) {
                int row = mt * 16 + lk * 4 + r;
                float iv = sigm(acc[0][ns][mt][r] + bi[ns]);
                float ov = sigm(acc[1][ns][mt][r] + bo[ns]);
                float uv = fmaxf(acc[2][ns][mt][r] + bu[ns], 0.f);
                float cv = iv * uv;
                float hv = ov * fmaxf(cv, 0.f);
                Hs[row * 136 + d] = f2b(hv);
                Cs[row * 136 + d] = f2b(cv);
            }
        }
    __syncthreads();

    size_t gbase = (size_t)b * 64 * 128;
    for (int e = tid * 8; e < 8192; e += 2048) {
        int row = e >> 7, d = e & 127;
        *(bf16x8*)(h_all + gbase + e) = *(const bf16x8*)&Hs[row * 136 + d];
        *(bf16x8*)(c_all + gbase + e) = *(const bf16x8*)&Cs[row * 136 + d];
    }
}

// ---------------------------------------------------------------------------
// K4: tree level, MFMA. Block = 32 output rows (64 input rows), 4 waves.
// N = 640 (i,o,u,f1,f2 x 128); wave w owns d in [32w,32w+32) of each gate.
// ---------------------------------------------------------------------------
__global__ __launch_bounds__(256) void k_tree(
    const bf16x8* __restrict__ BpkT, const float* __restrict__ tb,
    const float* __restrict__ Uf1_b, const float* __restrict__ Uf2_b,
    u16* __restrict__ h_all, u16* __restrict__ c_all,
    int in_off, int out_off, int n_out)
{
    __shared__ __align__(16) u16 A2[32 * KPT];   // 16,896 B
    __shared__ __align__(16) u16 C2[32 * KPT];   // 16,896 B
    __shared__ __align__(16) u16 Hs[32 * 136];   //  8,704 B
    __shared__ __align__(16) u16 Cs[32 * 136];   //  8,704 B
    const int tid = threadIdx.x, b = blockIdx.x;
    const int base = b * 32;

    // stage 64 input rows of h (as A: row r = [h[2r] | h[2r+1]]) and c.
    const u16* hsrc = h_all + (size_t)(in_off + base * 2) * 128;
    const u16* csrc = c_all + (size_t)(in_off + base * 2) * 128;
    for (int e = tid * 8; e < 8192; e += 2048) {
        int rr = e >> 7, cc = e & 127;
        int r = rr >> 1, k = (rr & 1) * 128 + cc;
        *(bf16x8*)&A2[r * KPT + k] = *(const bf16x8*)(hsrc + e);
        *(bf16x8*)&C2[r * KPT + k] = *(const bf16x8*)(csrc + e);
    }
    __syncthreads();

    const int wv = tid >> 6, l = tid & 63;
    const int lm = l & 15, lk = l >> 4;

    f32x4 acc[5][2][2];
    #pragma unroll
    for (int g = 0; g < 5; ++g)
        #pragma unroll
        for (int ns = 0; ns < 2; ++ns)
            #pragma unroll
            for (int mt = 0; mt < 2; ++mt)
                acc[g][ns][mt] = (f32x4){0.f, 0.f, 0.f, 0.f};

    for (int kc = 0; kc < 8; ++kc) {
        bf16x8 a[2];
        #pragma unroll
        for (int mt = 0; mt < 2; ++mt)
            a[mt] = *(const bf16x8*)&A2[(mt * 16 + lm) * KPT + kc * 32 + lk * 8];
        bf16x8 bf[5][2];
        #pragma unroll
        for (int g = 0; g < 5; ++g)
            #pragma unroll
            for (int ns = 0; ns < 2; ++ns) {
                int nt = g * 8 + wv * 2 + ns;
                bf[g][ns] = BpkT[(kc * 40 + nt) * 64 + l];
            }
        #pragma unroll
        for (int g = 0; g < 5; ++g)
            #pragma unroll
            for (int ns = 0; ns < 2; ++ns)
                #pragma unroll
                for (int mt = 0; mt < 2; ++mt)
                    acc[g][ns][mt] = __builtin_amdgcn_mfma_f32_16x16x32_bf16(
                        a[mt], bf[g][ns], acc[g][ns][mt], 0, 0, 0);
    }

    // epilogue (Hs/Cs are separate buffers; C2 reads race-free)
    #pragma unroll
    for (int ns = 0; ns < 2; ++ns) {
        int d = wv * 32 + ns * 16 + lm;
        float tbi = tb[d], tbo = tb[128 + d], tbu = tb[256 + d];
        float fb1 = Uf1_b[d], fb2 = Uf2_b[d];
        #pragma unroll
        for (int mt = 0; mt < 2; ++mt)
            #pragma unroll
            for (int r = 0; r < 4; ++r) {
                int row = mt * 16 + lk * 4 + r;
                float lc = b2f(C2[row * KPT + d]);
                float rc = b2f(C2[row * KPT + 128 + d]);
                float iv = sigm(acc[0][ns][mt][r] + tbi);
                float ov = sigm(acc[1][ns][mt][r] + tbo);
                float uv = fmaxf(acc[2][ns][mt][r] + tbu, 0.f);
                float f1 = sigm(acc[3][ns][mt][r] + fb1);
                float f2 = sigm(acc[4][ns][mt][r] + fb2);
                float cv = iv * uv + f1 * lc + f2 * rc;
                float hv = ov * fmaxf(cv, 0.f);
                Hs[row * 136 + d] = f2b(hv);
                Cs[row * 136 + d] = f2b(cv);
            }
    }
    __syncthreads();

    size_t gbase = (size_t)(out_off + base) * 128;
    for (int e = tid * 8; e < 4096; e += 2048) {
        int row = e >> 7, d = e & 127;
        if (base + row < n_out) {
            *(bf16x8*)(h_all + gbase + e) = *(const bf16x8*)&Hs[row * 136 + d];
            *(bf16x8*)(c_all + gbase + e) = *(const bf16x8*)&Cs[row * 136 + d];
        }
    }
}

// ---------------------------------------------------------------------------
// K5: projection of all 262143 h rows -> (row, 3) f32 output.
// ---------------------------------------------------------------------------
__global__ __launch_bounds__(256) void k_proj(
    const u16* __restrict__ h_all, const float* __restrict__ proj_w,
    const float* __restrict__ proj_b, float* __restrict__ out)
{
    int tid = threadIdx.x;
    int lane = tid & 63;
    int gw = blockIdx.x * 4 + (tid >> 6);
    float pw[3][2], pb[3];
    #pragma unroll
    for (int j = 0; j < 3; ++j) {
        pw[j][0] = proj_w[j * 128 + 2 * lane];
        pw[j][1] = proj_w[j * 128 + 2 * lane + 1];
        pb[j] = proj_b[j];
    }
    for (int row = gw; row < N_ALL; row += 4096) {
        u32 hv = *(const u32*)&h_all[(size_t)row * 128 + 2 * lane];
        float h0 = lo2f(hv), h1 = hi2f(hv);
        float p0 = pw[0][0] * h0 + pw[0][1] * h1;
        float p1 = pw[1][0] * h0 + pw[1][1] * h1;
        float p2 = pw[2][0] * h0 + pw[2][1] * h1;
        #pragma unroll
        for (int off = 32; off > 0; off >>= 1) {
            p0 += __shfl_xor(p0, off);
            p1 += __shfl_xor(p1, off);
            p2 += __shfl_xor(p2, off);
        }
        if (lane == 0) {
            out[(size_t)row * 3 + 0] = p0 + pb[0];
            out[(size_t)row * 3 + 1] = p1 + pb[1];
            out[(size_t)row * 3 + 2] = p2 + pb[2];
        }
    }
}

// ---------------------------------------------------------------------------
extern "C" void kernel_launch(void* const* d_in, const int* in_sizes, int n_in,
                              void* d_out, int out_size, void* d_ws, size_t ws_size,
                              hipStream_t stream)
{
    const float* emb    = (const float*)d_in[0];
    const float* Wi_w   = (const float*)d_in[1];
    const float* Wi_b   = (const float*)d_in[2];
    const float* Wo_w   = (const float*)d_in[3];
    const float* Wo_b   = (const float*)d_in[4];
    const float* Wu_w   = (const float*)d_in[5];
    const float* Wu_b   = (const float*)d_in[6];
    const float* Ui_w   = (const float*)d_in[7];
    const float* Ui_b   = (const float*)d_in[8];
    const float* Uo_w   = (const float*)d_in[9];
    const float* Uo_b   = (const float*)d_in[10];
    const float* Uu_w   = (const float*)d_in[11];
    const float* Uu_b   = (const float*)d_in[12];
    const float* Uf1_w  = (const float*)d_in[13];
    const float* Uf1_b  = (const float*)d_in[14];
    const float* Uf2_w  = (const float*)d_in[15];
    const float* Uf2_b  = (const float*)d_in[16];
    const float* wih    = (const float*)d_in[17];
    const float* whh    = (const float*)d_in[18];
    const float* bih    = (const float*)d_in[19];
    const float* bhh    = (const float*)d_in[20];
    const float* proj_w = (const float*)d_in[21];
    const float* proj_b = (const float*)d_in[22];
    const int* toks     = (const int*)d_in[23];
    const int* tgts     = (const int*)d_in[24];

    char* ws = (char*)d_ws;
    u16*   h_all = (u16*)(ws);                    // 262144*128*2 = 67,108,864 B
    u16*   c_all = (u16*)(ws + 67108864);         // 67,108,864 B
    u16*   BpkL  = (u16*)(ws + 134217728);        // 245,760 B
    u16*   BpkT  = (u16*)(ws + 134463488);        // 327,680 B
    float* xz    = (float*)(ws + 134791168);      // 102,400 B
    float* tb    = (float*)(ws + 134893568);      // 1,536 B -> total 134,895,104 B

    k_packL<<<60, 256, 0, stream>>>(Wi_w, Wo_w, Wu_w, BpkL);
    k_packT<<<80, 256, 0, stream>>>(Ui_w, Uo_w, Uu_w, Uf1_w, Uf2_w, BpkT);
    k_xz<<<50, 256, 0, stream>>>(emb, wih, bih, bhh, tgts, xz);
    k_lstm<<<1, 256, 0, stream>>>(whh, xz, Ui_w, Uo_w, Uu_w, Ui_b, Uo_b, Uu_b, tb);
    k_leaf<<<2048, 256, 0, stream>>>(emb, toks, (const bf16x8*)BpkL,
                                     Wi_b, Wo_b, Wu_b, h_all, c_all);

    int in_off = 0, n = L_LEAF, out_off = L_LEAF;
    for (int lvl = 0; lvl < 17; ++lvl) {
        int n_out = n >> 1;
        int blocks = (n_out + 31) / 32;
        k_tree<<<blocks, 256, 0, stream>>>((const bf16x8*)BpkT, tb, Uf1_b, Uf2_b,
                                           h_all, c_all, in_off, out_off, n_out);
        in_off = out_off; out_off += n_out; n = n_out;
    }

    k_proj<<<1024, 256, 0, stream>>>(h_all, proj_w, proj_b, (float*)d_out);
}

// Round 6
// 450.547 us; speedup vs baseline: 3.5518x; 1.1342x over previous
//
#include <hip/hip_runtime.h>
#include <hip/hip_bf16.h>
#include <math.h>

typedef unsigned short u16;
typedef unsigned int   u32;
typedef __attribute__((ext_vector_type(8))) short bf16x8;
typedef __attribute__((ext_vector_type(4))) float f32x4;

#define L_LEAF 131072
#define N_ALL  262143
#define KPL 328   // leaf A-tile LDS row stride (elems): 320 + 8 pad
#define KPT 264   // tree A/C-tile LDS row stride: 256 + 8 pad

__device__ __forceinline__ float b2f(u16 u) {
    u32 x = ((u32)u) << 16;
    return __builtin_bit_cast(float, x);
}
__device__ __forceinline__ float lo2f(u32 p) { u32 x = p << 16;          return __builtin_bit_cast(float, x); }
__device__ __forceinline__ float hi2f(u32 p) { u32 x = p & 0xffff0000u;  return __builtin_bit_cast(float, x); }
__device__ __forceinline__ u16 f2b(float f) {
    u32 x = __builtin_bit_cast(u32, f);
    u32 r = x + 0x7fffu + ((x >> 16) & 1u);
    return (u16)(r >> 16);
}
__device__ __forceinline__ u32 pack2(float a, float b) {
    return (u32)f2b(a) | ((u32)f2b(b) << 16);
}
// fast gates: v_exp_f32 computes 2^x; v_rcp_f32 ~1ulp. err ~1e-6, fine for tol.
__device__ __forceinline__ float fsigm(float x) {
    return __builtin_amdgcn_rcpf(1.f + __builtin_amdgcn_exp2f(x * -1.44269504f));
}
__device__ __forceinline__ float ftanh(float x) {
    return 1.f - 2.f * __builtin_amdgcn_rcpf(__builtin_amdgcn_exp2f(x * 2.88539008f) + 1.f);
}

// ---------------------------------------------------------------------------
// K0a: build leaf B-pack. BpkL[kc][nt][lane][8] bf16, kc<10, nt<24.
// ---------------------------------------------------------------------------
__global__ __launch_bounds__(256) void k_packL(
    const float* __restrict__ Wi_w, const float* __restrict__ Wo_w,
    const float* __restrict__ Wu_w, u16* __restrict__ BpkL)
{
    int gid = blockIdx.x * 256 + threadIdx.x;
    if (gid >= 15360) return;
    int l  = gid & 63;
    int nt = (gid >> 6) % 24;
    int kc = gid / (24 * 64);
    int n  = nt * 16 + (l & 15);
    int g  = n >> 7, d = n & 127;
    int k0 = kc * 32 + (l >> 4) * 8;
    const float* W = (g == 0) ? Wi_w : (g == 1) ? Wo_w : Wu_w;
    #pragma unroll
    for (int j = 0; j < 8; ++j) {
        int k = k0 + j;
        float v = (k < 300) ? W[d * 300 + k] : 0.f;
        BpkL[(size_t)gid * 8 + j] = f2b(v);
    }
}

// ---------------------------------------------------------------------------
// K0b: build tree B-pack. BpkT[kc][nt][lane][8] bf16, kc<8, nt<40.
// ---------------------------------------------------------------------------
__global__ __launch_bounds__(256) void k_packT(
    const float* __restrict__ Ui_w, const float* __restrict__ Uo_w,
    const float* __restrict__ Uu_w, const float* __restrict__ Uf1_w,
    const float* __restrict__ Uf2_w, u16* __restrict__ BpkT)
{
    int gid = blockIdx.x * 256 + threadIdx.x;
    if (gid >= 20480) return;
    int l  = gid & 63;
    int nt = (gid >> 6) % 40;
    int kc = gid / (40 * 64);
    int n  = nt * 16 + (l & 15);
    int g  = n >> 7, d = n & 127;
    int k0 = kc * 32 + (l >> 4) * 8;
    #pragma unroll
    for (int j = 0; j < 8; ++j) {
        int k = k0 + j;
        float v;
        if (g == 0)      v = Ui_w[d * 384 + k];
        else if (g == 1) v = Uo_w[d * 384 + k];
        else if (g == 2) v = Uu_w[d * 384 + k];
        else if (g == 3) v = (k < 128)  ? Uf1_w[d * 128 + k]       : 0.f;
        else             v = (k >= 128) ? Uf2_w[d * 128 + (k-128)] : 0.f;
        BpkT[(size_t)gid * 8 + j] = f2b(v);
    }
}

// ---------------------------------------------------------------------------
// K1: xz[t][j] = lstm_wih[j,:] @ emb[targets[t]] + bih[j] + bhh[j]   (f32)
// ---------------------------------------------------------------------------
__global__ __launch_bounds__(256) void k_xz(
    const float* __restrict__ emb, const float* __restrict__ wih,
    const float* __restrict__ bih, const float* __restrict__ bhh,
    const int* __restrict__ targets, float* __restrict__ xz)
{
    __shared__ float te[300];
    int t = blockIdx.x, tid = threadIdx.x;
    int tgt = targets[t];
    if (tid < 75) {
        float4 v = *(const float4*)(emb + (size_t)tgt * 300 + tid * 4);
        te[tid * 4 + 0] = v.x; te[tid * 4 + 1] = v.y;
        te[tid * 4 + 2] = v.z; te[tid * 4 + 3] = v.w;
    }
    __syncthreads();
    for (int rep = 0; rep < 2; ++rep) {
        int j = tid + rep * 256;
        float acc = bih[j] + bhh[j];
        const float* wr = wih + (size_t)j * 300;
        for (int k4 = 0; k4 < 75; ++k4) {
            float4 wv = *(const float4*)(wr + k4 * 4);
            float4 tv = *(const float4*)&te[k4 * 4];
            acc = fmaf(wv.x, tv.x, acc);
            acc = fmaf(wv.y, tv.y, acc);
            acc = fmaf(wv.z, tv.z, acc);
            acc = fmaf(wv.w, tv.w, acc);
        }
        xz[t * 512 + j] = acc;
    }
}

// ---------------------------------------------------------------------------
// K3: fused leaf (blocks 0..2047, MFMA) + sequential LSTM (block 2048).
// ---------------------------------------------------------------------------
__global__ __launch_bounds__(256) void k_fused(
    const float* __restrict__ emb, const int* __restrict__ toks,
    const bf16x8* __restrict__ BpkL,
    const float* __restrict__ Wi_b, const float* __restrict__ Wo_b, const float* __restrict__ Wu_b,
    u16* __restrict__ h_all, u16* __restrict__ c_all,
    const float* __restrict__ whh, const float* __restrict__ xz,
    const float* __restrict__ Ui_w, const float* __restrict__ Uo_w, const float* __restrict__ Uu_w,
    const float* __restrict__ Ui_b, const float* __restrict__ Uo_b, const float* __restrict__ Uu_b,
    float* __restrict__ tb)
{
    __shared__ __align__(16) u16 Atile[64 * KPL];   // 41,984 B
    const int tid = threadIdx.x, b = blockIdx.x;

    if (b >= 2048) {
        // ------------------ LSTM path (one block) ------------------
        float* h_lds = (float*)Atile;        // [128]
        float* z_lds = h_lds + 128;          // [512]

        u32 w0[64], w1[64];
        #pragma unroll
        for (int k2 = 0; k2 < 64; ++k2) {
            w0[k2] = pack2(whh[(size_t)tid * 128 + 2 * k2],
                           whh[(size_t)tid * 128 + 2 * k2 + 1]);
            w1[k2] = pack2(whh[(size_t)(tid + 256) * 128 + 2 * k2],
                           whh[(size_t)(tid + 256) * 128 + 2 * k2 + 1]);
        }
        float c0 = 0.f;
        if (tid < 128) h_lds[tid] = 0.f;
        __syncthreads();

        float nx0 = xz[tid], nx1 = xz[tid + 256];
        for (int t = 0; t < 50; ++t) {
            float x0 = nx0, x1 = nx1;
            if (t < 49) {
                nx0 = xz[(t + 1) * 512 + tid];
                nx1 = xz[(t + 1) * 512 + tid + 256];
            }
            // 4 independent chains (len 64), 2 pipelined b128 LDS reads/iter
            float a0A = x0, a0B = 0.f, a1A = x1, a1B = 0.f;
            const float4* h4 = (const float4*)h_lds;
            #pragma unroll
            for (int j = 0; j < 16; ++j) {
                float4 hA = h4[j];
                float4 hB = h4[j + 16];
                u32 wa0 = w0[2*j],      wa1 = w0[2*j + 1];
                u32 wb0 = w0[2*j + 32], wb1 = w0[2*j + 33];
                u32 va0 = w1[2*j],      va1 = w1[2*j + 1];
                u32 vb0 = w1[2*j + 32], vb1 = w1[2*j + 33];
                a0A = fmaf(lo2f(wa0), hA.x, a0A);
                a0A = fmaf(hi2f(wa0), hA.y, a0A);
                a0A = fmaf(lo2f(wa1), hA.z, a0A);
                a0A = fmaf(hi2f(wa1), hA.w, a0A);
                a0B = fmaf(lo2f(wb0), hB.x, a0B);
                a0B = fmaf(hi2f(wb0), hB.y, a0B);
                a0B = fmaf(lo2f(wb1), hB.z, a0B);
                a0B = fmaf(hi2f(wb1), hB.w, a0B);
                a1A = fmaf(lo2f(va0), hA.x, a1A);
                a1A = fmaf(hi2f(va0), hA.y, a1A);
                a1A = fmaf(lo2f(va1), hA.z, a1A);
                a1A = fmaf(hi2f(va1), hA.w, a1A);
                a1B = fmaf(lo2f(vb0), hB.x, a1B);
                a1B = fmaf(hi2f(vb0), hB.y, a1B);
                a1B = fmaf(lo2f(vb1), hB.z, a1B);
                a1B = fmaf(hi2f(vb1), hB.w, a1B);
            }
            z_lds[tid] = a0A + a0B;
            z_lds[tid + 256] = a1A + a1B;
            __syncthreads();
            if (tid < 128) {
                float zi = z_lds[tid], zf = z_lds[128 + tid];
                float zg = z_lds[256 + tid], zo = z_lds[384 + tid];
                c0 = fsigm(zf) * c0 + fsigm(zi) * ftanh(zg);
                h_lds[tid] = fsigm(zo) * ftanh(c0);
            }
            __syncthreads();
        }

        for (int rep = 0; rep < 2; ++rep) {
            int j = tid + rep * 256;
            if (j >= 384) break;
            int g = j >> 7, dd = j & 127;
            const float* W = (g == 0) ? Ui_w : (g == 1) ? Uo_w : Uu_w;
            const float* B = (g == 0) ? Ui_b : (g == 1) ? Uo_b : Uu_b;
            float acc = B[dd];
            for (int k = 0; k < 128; ++k)
                acc = fmaf(W[dd * 384 + 256 + k], h_lds[k], acc);
            tb[j] = acc;
        }
        return;
    }

    // ------------------ leaf path ------------------
    {   // stage 64 emb rows (f32 -> bf16); 4 threads per row
        int row = tid >> 2, sub = tid & 3;
        int tok = toks[b * 64 + row];
        const float* src = emb + (size_t)tok * 300;
        u16* dst = Atile + row * KPL;
        for (int i4 = sub; i4 < 75; i4 += 4) {
            float4 v = *(const float4*)(src + i4 * 4);
            ushort4 o;
            o.x = f2b(v.x); o.y = f2b(v.y); o.z = f2b(v.z); o.w = f2b(v.w);
            *(ushort4*)(dst + i4 * 4) = o;
        }
        if (sub == 0) {
            ushort4 z = {0, 0, 0, 0};
            #pragma unroll
            for (int p = 0; p < 5; ++p) *(ushort4*)(dst + 300 + p * 4) = z;
        }
    }
    __syncthreads();

    const int wv = tid >> 6, l = tid & 63;
    const int lm = l & 15, lk = l >> 4;

    f32x4 acc[3][2][4];
    #pragma unroll
    for (int g = 0; g < 3; ++g)
        #pragma unroll
        for (int ns = 0; ns < 2; ++ns)
            #pragma unroll
            for (int mt = 0; mt < 4; ++mt)
                acc[g][ns][mt] = (f32x4){0.f, 0.f, 0.f, 0.f};

    for (int kc = 0; kc < 10; ++kc) {
        bf16x8 a[4];
        #pragma unroll
        for (int mt = 0; mt < 4; ++mt)
            a[mt] = *(const bf16x8*)&Atile[(mt * 16 + lm) * KPL + kc * 32 + lk * 8];
        bf16x8 bf[3][2];
        #pragma unroll
        for (int g = 0; g < 3; ++g)
            #pragma unroll
            for (int ns = 0; ns < 2; ++ns) {
                int nt = g * 8 + wv * 2 + ns;
                bf[g][ns] = BpkL[(kc * 24 + nt) * 64 + l];
            }
        #pragma unroll
        for (int g = 0; g < 3; ++g)
            #pragma unroll
            for (int ns = 0; ns < 2; ++ns)
                #pragma unroll
                for (int mt = 0; mt < 4; ++mt)
                    acc[g][ns][mt] = __builtin_amdgcn_mfma_f32_16x16x32_bf16(
                        a[mt], bf[g][ns], acc[g][ns][mt], 0, 0, 0);
    }
    __syncthreads();

    u16* Hs = Atile;               // [64][136]
    u16* Cs = Atile + 64 * 136;    // [64][136]
    float bi[2], bo[2], bu[2];
    #pragma unroll
    for (int ns = 0; ns < 2; ++ns) {
        int d = wv * 32 + ns * 16 + lm;
        bi[ns] = Wi_b[d]; bo[ns] = Wo_b[d]; bu[ns] = Wu_b[d];
    }
    #pragma unroll
    for (int mt = 0; mt < 4; ++mt)
        #pragma unroll
        for (int ns = 0; ns < 2; ++ns) {
            int d = wv * 32 + ns * 16 + lm;
            #pragma unroll
            for (int r = 0; r < 4; ++r) {
                int row = mt * 16 + lk * 4 + r;
                float iv = fsigm(acc[0][ns][mt][r] + bi[ns]);
                float ov = fsigm(acc[1][ns][mt][r] + bo[ns]);
                float uv = fmaxf(acc[2][ns][mt][r] + bu[ns], 0.f);
                float cv = iv * uv;
                float hv = ov * fmaxf(cv, 0.f);
                Hs[row * 136 + d] = f2b(hv);
                Cs[row * 136 + d] = f2b(cv);
            }
        }
    __syncthreads();

    size_t gbase = (size_t)b * 64 * 128;
    for (int e = tid * 8; e < 8192; e += 2048) {
        int row = e >> 7, d = e & 127;
        *(bf16x8*)(h_all + gbase + e) = *(const bf16x8*)&Hs[row * 136 + d];
        *(bf16x8*)(c_all + gbase + e) = *(const bf16x8*)&Cs[row * 136 + d];
    }
}

// ---------------------------------------------------------------------------
// tree chunk: 32 output rows at (out_off+base) from 64 input rows (in_off+2*base)
// ---------------------------------------------------------------------------
__device__ __forceinline__ void tree_chunk(
    const bf16x8* __restrict__ BpkT, const float* __restrict__ tb,
    const float* __restrict__ Uf1_b, const float* __restrict__ Uf2_b,
    u16* __restrict__ h_all, u16* __restrict__ c_all,
    int in_off, int out_off, int n_out, int base, int tid,
    u16* A2, u16* C2, u16* Hs, u16* Cs)
{
    const u16* hsrc = h_all + (size_t)(in_off + base * 2) * 128;
    const u16* csrc = c_all + (size_t)(in_off + base * 2) * 128;
    int avail = 2 * (n_out - base); if (avail > 64) avail = 64;
    int lim = avail * 128;
    for (int e = tid * 8; e < 8192; e += 2048) {
        int rr = e >> 7, cc = e & 127;
        int r = rr >> 1, k = (rr & 1) * 128 + cc;
        bf16x8 vh = (bf16x8){0,0,0,0,0,0,0,0}, vc = vh;
        if (e < lim) {
            vh = *(const bf16x8*)(hsrc + e);
            vc = *(const bf16x8*)(csrc + e);
        }
        *(bf16x8*)&A2[r * KPT + k] = vh;
        *(bf16x8*)&C2[r * KPT + k] = vc;
    }
    __syncthreads();

    const int wv = tid >> 6, l = tid & 63;
    const int lm = l & 15, lk = l >> 4;

    f32x4 acc[5][2][2];
    #pragma unroll
    for (int g = 0; g < 5; ++g)
        #pragma unroll
        for (int ns = 0; ns < 2; ++ns)
            #pragma unroll
            for (int mt = 0; mt < 2; ++mt)
                acc[g][ns][mt] = (f32x4){0.f, 0.f, 0.f, 0.f};

    for (int kc = 0; kc < 8; ++kc) {
        bf16x8 a[2];
        #pragma unroll
        for (int mt = 0; mt < 2; ++mt)
            a[mt] = *(const bf16x8*)&A2[(mt * 16 + lm) * KPT + kc * 32 + lk * 8];
        bf16x8 bf[5][2];
        #pragma unroll
        for (int g = 0; g < 5; ++g)
            #pragma unroll
            for (int ns = 0; ns < 2; ++ns) {
                int nt = g * 8 + wv * 2 + ns;
                bf[g][ns] = BpkT[(kc * 40 + nt) * 64 + l];
            }
        #pragma unroll
        for (int g = 0; g < 5; ++g)
            #pragma unroll
            for (int ns = 0; ns < 2; ++ns)
                #pragma unroll
                for (int mt = 0; mt < 2; ++mt)
                    acc[g][ns][mt] = __builtin_amdgcn_mfma_f32_16x16x32_bf16(
                        a[mt], bf[g][ns], acc[g][ns][mt], 0, 0, 0);
    }

    #pragma unroll
    for (int ns = 0; ns < 2; ++ns) {
        int d = wv * 32 + ns * 16 + lm;
        float tbi = tb[d], tbo = tb[128 + d], tbu = tb[256 + d];
        float fb1 = Uf1_b[d], fb2 = Uf2_b[d];
        #pragma unroll
        for (int mt = 0; mt < 2; ++mt)
            #pragma unroll
            for (int r = 0; r < 4; ++r) {
                int row = mt * 16 + lk * 4 + r;
                float lc = b2f(C2[row * KPT + d]);
                float rc = b2f(C2[row * KPT + 128 + d]);
                float iv = fsigm(acc[0][ns][mt][r] + tbi);
                float ov = fsigm(acc[1][ns][mt][r] + tbo);
                float uv = fmaxf(acc[2][ns][mt][r] + tbu, 0.f);
                float f1 = fsigm(acc[3][ns][mt][r] + fb1);
                float f2 = fsigm(acc[4][ns][mt][r] + fb2);
                float cv = iv * uv + f1 * lc + f2 * rc;
                float hv = ov * fmaxf(cv, 0.f);
                Hs[row * 136 + d] = f2b(hv);
                Cs[row * 136 + d] = f2b(cv);
            }
    }
    __syncthreads();

    size_t gbase = (size_t)(out_off + base) * 128;
    for (int e = tid * 8; e < 4096; e += 2048) {
        int row = e >> 7, d = e & 127;
        if (base + row < n_out) {
            *(bf16x8*)(h_all + gbase + e) = *(const bf16x8*)&Hs[row * 136 + d];
            *(bf16x8*)(c_all + gbase + e) = *(const bf16x8*)&Cs[row * 136 + d];
        }
    }
}

// ---------------------------------------------------------------------------
// K4: one tree level (n_out >= 64).
// ---------------------------------------------------------------------------
__global__ __launch_bounds__(256) void k_tree(
    const bf16x8* __restrict__ BpkT, const float* __restrict__ tb,
    const float* __restrict__ Uf1_b, const float* __restrict__ Uf2_b,
    u16* __restrict__ h_all, u16* __restrict__ c_all,
    int in_off, int out_off, int n_out)
{
    __shared__ __align__(16) u16 A2[32 * KPT];
    __shared__ __align__(16) u16 C2[32 * KPT];
    __shared__ __align__(16) u16 Hs[32 * 136];
    __shared__ __align__(16) u16 Cs[32 * 136];
    tree_chunk(BpkT, tb, Uf1_b, Uf2_b, h_all, c_all,
               in_off, out_off, n_out, blockIdx.x * 32, threadIdx.x,
               A2, C2, Hs, Cs);
}

// ---------------------------------------------------------------------------
// K4b: fused tail levels (n_out = 32,16,8,4,2,1) in ONE block.
// Intra-block global RAW across __syncthreads() is workgroup-scope coherent.
// ---------------------------------------------------------------------------
__global__ __launch_bounds__(256) void k_tree_tail(
    const bf16x8* __restrict__ BpkT, const float* __restrict__ tb,
    const float* __restrict__ Uf1_b, const float* __restrict__ Uf2_b,
    u16* __restrict__ h_all, u16* __restrict__ c_all,
    int in_off0, int out_off0, int n0)
{
    __shared__ __align__(16) u16 A2[32 * KPT];
    __shared__ __align__(16) u16 C2[32 * KPT];
    __shared__ __align__(16) u16 Hs[32 * 136];
    __shared__ __align__(16) u16 Cs[32 * 136];
    int in_off = in_off0, out_off = out_off0, n_out = n0;
    while (n_out >= 1) {
        tree_chunk(BpkT, tb, Uf1_b, Uf2_b, h_all, c_all,
                   in_off, out_off, n_out, 0, threadIdx.x, A2, C2, Hs, Cs);
        in_off = out_off; out_off += n_out; n_out >>= 1;
        __syncthreads();
    }
}

// ---------------------------------------------------------------------------
// K5: projection of all 262143 h rows -> (row, 3) f32 output.
// ---------------------------------------------------------------------------
__global__ __launch_bounds__(256) void k_proj(
    const u16* __restrict__ h_all, const float* __restrict__ proj_w,
    const float* __restrict__ proj_b, float* __restrict__ out)
{
    int tid = threadIdx.x;
    int lane = tid & 63;
    int gw = blockIdx.x * 4 + (tid >> 6);
    float pw[3][2], pb[3];
    #pragma unroll
    for (int j = 0; j < 3; ++j) {
        pw[j][0] = proj_w[j * 128 + 2 * lane];
        pw[j][1] = proj_w[j * 128 + 2 * lane + 1];
        pb[j] = proj_b[j];
    }
    for (int row = gw; row < N_ALL; row += 4096) {
        u32 hv = *(const u32*)&h_all[(size_t)row * 128 + 2 * lane];
        float h0 = lo2f(hv), h1 = hi2f(hv);
        float p0 = pw[0][0] * h0 + pw[0][1] * h1;
        float p1 = pw[1][0] * h0 + pw[1][1] * h1;
        float p2 = pw[2][0] * h0 + pw[2][1] * h1;
        #pragma unroll
        for (int off = 32; off > 0; off >>= 1) {
            p0 += __shfl_xor(p0, off);
            p1 += __shfl_xor(p1, off);
            p2 += __shfl_xor(p2, off);
        }
        if (lane == 0) {
            out[(size_t)row * 3 + 0] = p0 + pb[0];
            out[(size_t)row * 3 + 1] = p1 + pb[1];
            out[(size_t)row * 3 + 2] = p2 + pb[2];
        }
    }
}

// ---------------------------------------------------------------------------
extern "C" void kernel_launch(void* const* d_in, const int* in_sizes, int n_in,
                              void* d_out, int out_size, void* d_ws, size_t ws_size,
                              hipStream_t stream)
{
    const float* emb    = (const float*)d_in[0];
    const float* Wi_w   = (const float*)d_in[1];
    const float* Wi_b   = (const float*)d_in[2];
    const float* Wo_w   = (const float*)d_in[3];
    const float* Wo_b   = (const float*)d_in[4];
    const float* Wu_w   = (const float*)d_in[5];
    const float* Wu_b   = (const float*)d_in[6];
    const float* Ui_w   = (const float*)d_in[7];
    const float* Ui_b   = (const float*)d_in[8];
    const float* Uo_w   = (const float*)d_in[9];
    const float* Uo_b   = (const float*)d_in[10];
    const float* Uu_w   = (const float*)d_in[11];
    const float* Uu_b   = (const float*)d_in[12];
    const float* Uf1_w  = (const float*)d_in[13];
    const float* Uf1_b  = (const float*)d_in[14];
    const float* Uf2_w  = (const float*)d_in[15];
    const float* Uf2_b  = (const float*)d_in[16];
    const float* wih    = (const float*)d_in[17];
    const float* whh    = (const float*)d_in[18];
    const float* bih    = (const float*)d_in[19];
    const float* bhh    = (const float*)d_in[20];
    const float* proj_w = (const float*)d_in[21];
    const float* proj_b = (const float*)d_in[22];
    const int* toks     = (const int*)d_in[23];
    const int* tgts     = (const int*)d_in[24];

    char* ws = (char*)d_ws;
    u16*   h_all = (u16*)(ws);                    // 262144*128*2 = 67,108,864 B
    u16*   c_all = (u16*)(ws + 67108864);         // 67,108,864 B
    u16*   BpkL  = (u16*)(ws + 134217728);        // 245,760 B
    u16*   BpkT  = (u16*)(ws + 134463488);        // 327,680 B
    float* xz    = (float*)(ws + 134791168);      // 102,400 B
    float* tb    = (float*)(ws + 134893568);      // 1,536 B -> total 134,895,104 B

    k_packL<<<60, 256, 0, stream>>>(Wi_w, Wo_w, Wu_w, BpkL);
    k_packT<<<80, 256, 0, stream>>>(Ui_w, Uo_w, Uu_w, Uf1_w, Uf2_w, BpkT);
    k_xz<<<50, 256, 0, stream>>>(emb, wih, bih, bhh, tgts, xz);
    k_fused<<<2049, 256, 0, stream>>>(emb, toks, (const bf16x8*)BpkL,
                                      Wi_b, Wo_b, Wu_b, h_all, c_all,
                                      whh, xz, Ui_w, Uo_w, Uu_w,
                                      Ui_b, Uo_b, Uu_b, tb);

    int in_off = 0, n = L_LEAF, out_off = L_LEAF;
    for (int lvl = 0; lvl < 11; ++lvl) {          // n_out = 65536 .. 64
        int n_out = n >> 1;
        k_tree<<<n_out / 32, 256, 0, stream>>>((const bf16x8*)BpkT, tb, Uf1_b, Uf2_b,
                                               h_all, c_all, in_off, out_off, n_out);
        in_off = out_off; out_off += n_out; n = n_out;
    }
    // tail: n_out = 32,16,8,4,2,1 fused in one block
    k_tree_tail<<<1, 256, 0, stream>>>((const bf16x8*)BpkT, tb, Uf1_b, Uf2_b,
                                       h_all, c_all, in_off, out_off, 32);

    k_proj<<<1024, 256, 0, stream>>>(h_all, proj_w, proj_b, (float*)d_out);
}